// Round 10
// baseline (291.469 us; speedup 1.0000x reference)
//
#include <hip/hip_runtime.h>
#include <hip/hip_bf16.h>

typedef __attribute__((ext_vector_type(8))) short short8;
typedef __attribute__((ext_vector_type(4))) float f32x4;

#define EDGE_CHUNK 4096
#define CAP 128   // fixed CSR capacity per node (Poisson(17) max << 128)

__device__ __forceinline__ float lrelu(float v) { return fmaxf(v, 0.2f * v); }

__device__ __forceinline__ short bf16_hi(float f, float* back) {
    __hip_bfloat16 h = __float2bfloat16(f);
    *back = __bfloat162float(h);
    return __builtin_bit_cast(short, h);
}
__device__ __forceinline__ short f2bf(float f) {
    return __builtin_bit_cast(short, __float2bfloat16(f));
}

// ================= device bodies =================

// ---- pack [W1|W1sd] and [W2|W2sd] -> MFMA B-fragment order, hi/lo bf16 ----
__device__ void packW_body(const float* __restrict__ W1, const float* __restrict__ a1s,
                           const float* __restrict__ a1d, const float* __restrict__ W2,
                           const float* __restrict__ a2s, const float* __restrict__ a2d,
                           short* __restrict__ w1hi, short* __restrict__ w1lo,
                           short* __restrict__ w2hi, short* __restrict__ w2lo, int t) {
    if (t < 256 * 144) {
        int j = t & 7, lane = (t >> 3) & 63, tile = t >> 9;
        int nt = tile % 9, kt = tile / 9;
        int k = kt * 32 + (lane >> 4) * 8 + j;
        int c = nt * 16 + (lane & 15);
        float w;
        if (c < 128) {
            w = W1[(size_t)k * 128 + c];
        } else {
            int hh = c - 128, h = hh & 7;
            const float* a = (hh >= 8) ? a1d : a1s;
            w = 0.f;
#pragma unroll
            for (int q = 0; q < 16; q++) w += W1[(size_t)k * 128 + h * 16 + q] * a[h * 16 + q];
        }
        float back;
        w1hi[t] = bf16_hi(w, &back);
        w1lo[t] = f2bf(w - back);
    } else {
        int u = t - 256 * 144;
        if (u >= 128 * 80) return;
        int j = u & 7, lane = (u >> 3) & 63, tile = u >> 9;
        int nt = tile % 5, kt = tile / 5;
        int k = kt * 32 + (lane >> 4) * 8 + j;
        int c = nt * 16 + (lane & 15);
        float w = 0.f;
        if (c < 64) {
            w = W2[(size_t)k * 64 + c];
        } else if (c < 66) {
            const float* a = (c == 65) ? a2d : a2s;
#pragma unroll
            for (int q = 0; q < 64; q++) w += W2[(size_t)k * 64 + q] * a[q];
        }
        float back;
        w2hi[u] = bf16_hi(w, &back);
        w2lo[u] = f2bf(w - back);
    }
}

// ---- XCD-partitioned direct-offset scatter: csr[d*CAP + pos], cursor==degree ----
__device__ void scatter_body(const int* __restrict__ ei, int E, int n,
                             int* __restrict__ cursor, int* __restrict__ csr_src, int vbid) {
    int slot = vbid & 7;
    int chunk = vbid >> 3;
    int lo = (int)(((long)n * slot) >> 3);
    int hi = (int)(((long)n * (slot + 1)) >> 3);
    int ET = E + n;
    int base = chunk * EDGE_CHUNK;
    int endi = min(base + EDGE_CHUNK, ET);
    for (int i = base + threadIdx.x; i < endi; i += 256) {
        int d = (i < E) ? ei[E + i] : i - E;
        if (d >= lo && d < hi) {
            int pos = atomicAdd(&cursor[d], 1);
            if (pos < CAP) {
                int s = (i < E) ? ei[i] : d;
                csr_src[(size_t)d * CAP + pos] = s;
            }
        }
    }
}

// ---- layer-1 MFMA GEMM body (LDS-staged coalesced epilogue) ----
template <int K, int NT>
__device__ void gemm1_body(const float* __restrict__ A, const short* __restrict__ Bhi,
                           const short* __restrict__ Blo, unsigned short* __restrict__ hb,
                           float* __restrict__ s_s, float* __restrict__ s_d, int M, int vbid) {
    constexpr int KT = K / 32;
    constexpr int NH = NT - 1;
    __shared__ __align__(16) unsigned short stage[4][16][NH * 16];
    const int wave = threadIdx.x >> 6, lane = threadIdx.x & 63;
    const int row0 = (vbid * 4 + wave) * 16;
    if (row0 >= M) return;
    const int arow = row0 + (lane & 15);
    const float* ap = A + (size_t)arow * K + (lane >> 4) * 8;

    f32x4 acc[NT];
#pragma unroll
    for (int i = 0; i < NT; i++) acc[i] = (f32x4){0.f, 0.f, 0.f, 0.f};

    for (int kt = 0; kt < KT; kt++) {
        float av[8];
        *(float4*)(av)     = *(const float4*)(ap + kt * 32);
        *(float4*)(av + 4) = *(const float4*)(ap + kt * 32 + 4);
        short8 ahi, alo;
#pragma unroll
        for (int j = 0; j < 8; j++) {
            float back;
            ahi[j] = bf16_hi(av[j], &back);
            alo[j] = f2bf(av[j] - back);
        }
        const short8* bh = (const short8*)(Bhi + ((size_t)(kt * NT) * 64 + lane) * 8);
        const short8* bl = (const short8*)(Blo + ((size_t)(kt * NT) * 64 + lane) * 8);
#pragma unroll
        for (int nt = 0; nt < NT; nt++) {
            short8 bhv = bh[nt * 64];
            short8 blv = bl[nt * 64];
            acc[nt] = __builtin_amdgcn_mfma_f32_16x16x32_bf16(ahi, bhv, acc[nt], 0, 0, 0);
            acc[nt] = __builtin_amdgcn_mfma_f32_16x16x32_bf16(ahi, blv, acc[nt], 0, 0, 0);
            acc[nt] = __builtin_amdgcn_mfma_f32_16x16x32_bf16(alo, bhv, acc[nt], 0, 0, 0);
        }
    }
    const int rgrp = (lane >> 4) * 4;
    const int col = lane & 15;
#pragma unroll
    for (int nt = 0; nt < NH; nt++)
#pragma unroll
        for (int r = 0; r < 4; r++)
            stage[wave][rgrp + r][nt * 16 + col] = (unsigned short)f2bf(acc[nt][r]);
    asm volatile("s_waitcnt lgkmcnt(0)" ::: "memory");
    {
        const uint4* srcp = (const uint4*)&stage[wave][0][0];
        uint4* dstp = (uint4*)(hb + (size_t)row0 * (NH * 16));
#pragma unroll
        for (int c = lane; c < NH * 32; c += 64) dstp[c] = srcp[c];
    }
#pragma unroll
    for (int r = 0; r < 4; r++) {
        int orow = row0 + rgrp + r;
        float v = acc[NH][r];
        if (col < 8) s_s[orow * 8 + col] = v;
        else         s_d[orow * 8 + (col - 8)] = v;
    }
}

// ================= kernels =================

__launch_bounds__(256)
__global__ void fused_pack_scatter(const float* __restrict__ W1, const float* __restrict__ a1s,
                                   const float* __restrict__ a1d, const float* __restrict__ W2,
                                   const float* __restrict__ a2s, const float* __restrict__ a2d,
                                   short* __restrict__ w1hi, short* __restrict__ w1lo,
                                   short* __restrict__ w2hi, short* __restrict__ w2lo,
                                   const int* __restrict__ ei, int E, int n,
                                   int* __restrict__ cursor, int* __restrict__ csr_src,
                                   int npack) {
    if ((int)blockIdx.x < npack) {
        int t = blockIdx.x * 256 + threadIdx.x;
        packW_body(W1, a1s, a1d, W2, a2s, a2d, w1hi, w1lo, w2hi, w2lo, t);
    } else {
        scatter_body(ei, E, n, cursor, csr_src, blockIdx.x - npack);
    }
}

__launch_bounds__(256)
__global__ void mfma_gemm1(const float* __restrict__ A, const short* __restrict__ Bhi,
                           const short* __restrict__ Blo, unsigned short* __restrict__ hb,
                           float* __restrict__ s_s, float* __restrict__ s_d, int M) {
    gemm1_body<256, 9>(A, Bhi, Blo, hb, s_s, s_d, M, blockIdx.x);
}

// ---- fused layer-1 gather + layer-2 GEMM ----
// 16 waves/block; wave wv gathers node blockIdx*16+wv (identical math to R9),
// splits post-ELU fp32 into hi/lo bf16 in registers, stores to padded LDS tile;
// after barrier, waves 0-4 run the 16x80 MFMA GEMM (split-bf16, same numerics).
__launch_bounds__(1024)
__global__ void gather1_gemm2(const int* __restrict__ degv, const int* __restrict__ csr_src,
                              const float* __restrict__ ssrc, const float* __restrict__ sdst,
                              const unsigned short* __restrict__ h1b,
                              const float* __restrict__ b1,
                              const short* __restrict__ w2hi, const short* __restrict__ w2lo,
                              unsigned short* __restrict__ h2b,
                              float* __restrict__ s2s, float* __restrict__ s2d, int n) {
    __shared__ __align__(16) unsigned short Ahi[16][136];  // +8 ush pad: bank-spread
    __shared__ __align__(16) unsigned short Alo[16][136];
    __shared__ __align__(16) unsigned short hstage[16][64];
    const int wv = threadIdx.x >> 6, lane = threadIdx.x & 63;
    const int row0g = blockIdx.x * 16;
    const int wid = row0g + wv;

    if (wid < n) {
        int eg = lane >> 3;
        int hs = lane & 7;
        int ha = lane >> 3;
        float sd_s = sdst[wid * 8 + hs];
        int dg = degv[wid]; if (dg > CAP) dg = CAP;
        int beg = wid * CAP, end = beg + dg;
        float den_p = 0.f, a0 = 0.f, a1 = 0.f;

        int idx0 = beg + eg;
        int src_c = (idx0 < end) ? csr_src[idx0] : 0;
        int src_n = (idx0 + 8 < end) ? csr_src[idx0 + 8] : 0;
        float sc_c = (idx0 < end) ? ssrc[src_c * 8 + hs] : 0.f;

        for (int i = beg; i < end; i += 8) {
            int src_n2 = (i + 16 + eg < end) ? csr_src[i + 16 + eg] : 0;
            float sc_n = (i + 8 + eg < end) ? ssrc[src_n * 8 + hs] : 0.f;
            float e = (i + eg < end) ? __expf(lrelu(sc_c + sd_s)) : 0.f;
            den_p += e;
            int nn = end - i;
#define G1_BODY(k)                                                                  \
            {                                                                       \
                float eb = __shfl(e, (k) * 8 + ha, 64);                             \
                int sb = __shfl(src_c, (k) * 8, 64);                                \
                unsigned xw = *(const unsigned*)(h1b + (size_t)sb * 128 + 2 * lane);\
                a0 = __builtin_fmaf(eb, __uint_as_float(xw << 16), a0);             \
                a1 = __builtin_fmaf(eb, __uint_as_float(xw & 0xffff0000u), a1);     \
            }
            if (nn >= 8) {
#pragma unroll
                for (int k = 0; k < 8; k++) G1_BODY(k)
            } else {
                for (int k = 0; k < nn; k++) G1_BODY(k)
            }
#undef G1_BODY
            src_c = src_n; src_n = src_n2; sc_c = sc_n;
        }
        den_p += __shfl_xor(den_p, 8, 64);
        den_p += __shfl_xor(den_p, 16, 64);
        den_p += __shfl_xor(den_p, 32, 64);
        float den = __shfl(den_p, ha, 64);
        float inv = 1.f / den;
        float2 bb = *(const float2*)(b1 + 2 * lane);
        float o0 = __builtin_fmaf(a0, inv, bb.x);
        float o1 = __builtin_fmaf(a1, inv, bb.y);
        o0 = o0 > 0.f ? o0 : (__expf(o0) - 1.f);
        o1 = o1 > 0.f ? o1 : (__expf(o1) - 1.f);
        // split hi/lo bf16 in registers (== what gemm2's A-conversion produced)
        float back0, back1;
        short h0 = bf16_hi(o0, &back0);
        short l0 = f2bf(o0 - back0);
        short h1 = bf16_hi(o1, &back1);
        short l1 = f2bf(o1 - back1);
        Ahi[wv][2 * lane]     = (unsigned short)h0;
        Ahi[wv][2 * lane + 1] = (unsigned short)h1;
        Alo[wv][2 * lane]     = (unsigned short)l0;
        Alo[wv][2 * lane + 1] = (unsigned short)l1;
    }
    __syncthreads();

    // ---- layer-2 GEMM phase: waves 0-4 each own one 16-col tile (nt = wv) ----
    if (wv < 5) {
        const int nt = wv;
        const int arow = lane & 15;
        const int kq = (lane >> 4) * 8;
        f32x4 acc = (f32x4){0.f, 0.f, 0.f, 0.f};
#pragma unroll
        for (int kt = 0; kt < 4; kt++) {
            short8 ahv = *(const short8*)&Ahi[arow][kt * 32 + kq];
            short8 alv = *(const short8*)&Alo[arow][kt * 32 + kq];
            short8 bhv = *(const short8*)(w2hi + ((size_t)(kt * 5 + nt) * 64 + lane) * 8);
            short8 blv = *(const short8*)(w2lo + ((size_t)(kt * 5 + nt) * 64 + lane) * 8);
            acc = __builtin_amdgcn_mfma_f32_16x16x32_bf16(ahv, bhv, acc, 0, 0, 0);
            acc = __builtin_amdgcn_mfma_f32_16x16x32_bf16(ahv, blv, acc, 0, 0, 0);
            acc = __builtin_amdgcn_mfma_f32_16x16x32_bf16(alv, bhv, acc, 0, 0, 0);
        }
        const int rgrp = (lane >> 4) * 4;
        const int col = lane & 15;
        if (nt < 4) {
#pragma unroll
            for (int r = 0; r < 4; r++)
                hstage[rgrp + r][nt * 16 + col] = (unsigned short)f2bf(acc[r]);
        } else {
#pragma unroll
            for (int r = 0; r < 4; r++) {
                int orow = row0g + rgrp + r;
                if (orow < n) {
                    if (col == 0)      s2s[orow] = acc[r];
                    else if (col == 1) s2d[orow] = acc[r];
                }
            }
        }
    }
    __syncthreads();
    // coalesced h2b write: 16 rows x 128B = 2KB (wave 0)
    if (wv == 0) {
        const uint4* srcp = (const uint4*)&hstage[0][0];
        uint4* dstp = (uint4*)(h2b + (size_t)row0g * 64);
        dstp[lane] = srcp[lane];
        dstp[lane + 64] = srcp[lane + 64];
    }
}

// ---- layer-2 gather + bias + log_softmax ----
__launch_bounds__(256)
__global__ void gather2_kernel(const int* __restrict__ degv, const int* __restrict__ csr_src,
                               const float* __restrict__ ssrc, const float* __restrict__ sdst,
                               const unsigned short* __restrict__ h2b,
                               const float* __restrict__ b2, float* __restrict__ out, int n) {
    int wid = blockIdx.x * 4 + (threadIdx.x >> 6);
    if (wid >= n) return;
    int lane = threadIdx.x & 63;
    float sd = sdst[wid];
    int dg = degv[wid]; if (dg > CAP) dg = CAP;
    int beg = wid * CAP, end = beg + dg;
    float den_p = 0.f, acc = 0.f;

    int idx0 = beg + lane;
    int src_c = (idx0 < end) ? csr_src[idx0] : 0;
    float sc_c = (idx0 < end) ? ssrc[src_c] : 0.f;

    for (int i = beg; i < end; i += 64) {
        float e = (i + lane < end) ? __expf(lrelu(sc_c + sd)) : 0.f;
        den_p += e;
        int nn = end - i; if (nn > 64) nn = 64;
#define G2_BODY(k)                                                                  \
        {                                                                           \
            float eb = __shfl(e, (k), 64);                                          \
            int sb = __shfl(src_c, (k), 64);                                        \
            float x = __uint_as_float(((unsigned)h2b[(size_t)sb * 64 + lane]) << 16);\
            acc = __builtin_fmaf(eb, x, acc);                                       \
        }
        int k = 0;
        for (; k + 8 <= nn; k += 8) {
#pragma unroll
            for (int u = 0; u < 8; u++) G2_BODY(k + u)
        }
        for (; k < nn; k++) G2_BODY(k)
#undef G2_BODY
        if (i + 64 < end) {
            int idx = i + 64 + lane;
            src_c = (idx < end) ? csr_src[idx] : 0;
            sc_c = (idx < end) ? ssrc[src_c] : 0.f;
        }
    }
#pragma unroll
    for (int off = 1; off < 64; off <<= 1) den_p += __shfl_xor(den_p, off, 64);

    float o = acc / den_p + b2[lane];
    float mx = o;
#pragma unroll
    for (int off = 32; off; off >>= 1) mx = fmaxf(mx, __shfl_xor(mx, off, 64));
    float ex = __expf(o - mx);
    float sum = ex;
#pragma unroll
    for (int off = 32; off; off >>= 1) sum += __shfl_xor(sum, off, 64);
    out[(size_t)wid * 64 + lane] = o - mx - logf(sum);
}

extern "C" void kernel_launch(void* const* d_in, const int* in_sizes, int n_in,
                              void* d_out, int out_size, void* d_ws, size_t ws_size,
                              hipStream_t stream) {
    const float* x   = (const float*)d_in[0];
    const int*   ei  = (const int*)d_in[1];
    const float* W1  = (const float*)d_in[2];
    const float* a1s = (const float*)d_in[3];
    const float* a1d = (const float*)d_in[4];
    const float* b1  = (const float*)d_in[5];
    const float* W2  = (const float*)d_in[6];
    const float* a2s = (const float*)d_in[7];
    const float* a2d = (const float*)d_in[8];
    const float* b2  = (const float*)d_in[9];
    float* out = (float*)d_out;

    const int n = in_sizes[0] / 256;   // 50000
    const int E = in_sizes[1] / 2;     // 800000
    const int ET = E + n;
    const int NCH = (ET + EDGE_CHUNK - 1) / EDGE_CHUNK;       // 208
    const int NPACK = (256 * 144 + 128 * 80) / 256;           // 184 (8-aligned)

    // workspace layout (out1 removed — layer-2 GEMM reads LDS)
    float* ws = (float*)d_ws;
    float* s1s  = ws;                          // n*8
    float* s1d  = s1s + (size_t)n * 8;         // n*8
    float* s2s  = s1d + (size_t)n * 8;         // n
    float* s2d  = s2s + n;                     // n
    unsigned short* h1b = (unsigned short*)(s2d + n);   // n*128 ushort
    unsigned short* h2b = h1b + (size_t)n * 128;        // n*64 ushort
    int*   cursor  = (int*)(h2b + (size_t)n * 64);      // n (memset; == degree after scatter)
    int*   csr_src = cursor + n;               // n*CAP
    short* w1hi    = (short*)(csr_src + (size_t)n * CAP);  // 256*144
    short* w1lo    = w1hi + 256 * 144;
    short* w2hi    = w1lo + 256 * 144;         // 128*80
    short* w2lo    = w2hi + 128 * 80;

    hipMemsetAsync(cursor, 0, (size_t)n * 4, stream);

    const int B = 256;

    // 1) weight pack + direct CSR scatter
    fused_pack_scatter<<<NPACK + 8 * NCH, B, 0, stream>>>(W1, a1s, a1d, W2, a2s, a2d,
                                                          w1hi, w1lo, w2hi, w2lo,
                                                          ei, E, n, cursor, csr_src, NPACK);
    // 2) layer-1 GEMM (h->bf16 + folded score projections, coalesced epilogue)
    mfma_gemm1<<<(n + 63) / 64, B, 0, stream>>>(x, w1hi, w1lo, h1b, s1s, s1d, n);
    // 3) layer-1 gather + layer-2 GEMM (fused; 16 nodes/block)
    gather1_gemm2<<<(n + 15) / 16, 1024, 0, stream>>>(cursor, csr_src, s1s, s1d, h1b, b1,
                                                      w2hi, w2lo, h2b, s2s, s2d, n);
    // 4) layer-2 gather + log_softmax
    gather2_kernel<<<(n + 3) / 4, B, 0, stream>>>(cursor, csr_src, s2s, s2d, h2b, b2, out, n);
}